// Round 3
// baseline (23386.986 us; speedup 1.0000x reference)
//
#include <hip/hip_runtime.h>
#include <hip/hip_cooperative_groups.h>

namespace cg = cooperative_groups;

#define HID   512
#define BATCH 256
#define SEQ   512
#define NBLK  192
#define NTHR  512
#define HARR  262144   // halves per (layer,parity) h array = 8 tiles x TILEH
#define TILEH 32768    // halves per 32-row batch tile (64 KiB)

typedef __attribute__((ext_vector_type(8))) _Float16 half8;
typedef __attribute__((ext_vector_type(16))) float f32x16;

typedef __attribute__((address_space(1))) const unsigned int kGlobU32;
typedef __attribute__((address_space(3))) unsigned int kLdsU32;

__device__ __forceinline__ float sigf(float x) { return 1.0f / (1.0f + __expf(-x)); }

__device__ __forceinline__ half8 cvt8(const float* p) {
  const float4 a = ((const float4*)p)[0];
  const float4 b = ((const float4*)p)[1];
  half8 r;
  r[0] = (_Float16)a.x; r[1] = (_Float16)a.y; r[2] = (_Float16)a.z; r[3] = (_Float16)a.w;
  r[4] = (_Float16)b.x; r[5] = (_Float16)b.y; r[6] = (_Float16)b.z; r[7] = (_Float16)b.w;
  return r;
}

// async global->LDS, 16 B per lane; lds dest = wave-uniform base + lane*16 (HW rule)
__device__ __forceinline__ void stage16(const _Float16* g, _Float16* l) {
  __builtin_amdgcn_global_load_lds((kGlobU32*)g, (kLdsU32*)l, 16, 0, 0);
}

__global__ __launch_bounds__(NTHR, 2)
void lstm3_persistent(const float* __restrict__ tracks,
                      const float* __restrict__ Wih0, const float* __restrict__ bih0,
                      const float* __restrict__ Whh0, const float* __restrict__ bhh0,
                      const float* __restrict__ Wih1, const float* __restrict__ bih1,
                      const float* __restrict__ Whh1, const float* __restrict__ bhh1,
                      const float* __restrict__ Wih2, const float* __restrict__ bih2,
                      const float* __restrict__ Whh2, const float* __restrict__ bhh2,
                      const float* __restrict__ Wpred, const float* __restrict__ bpred,
                      float* __restrict__ out, unsigned short* __restrict__ ws)
{
  // dynamic LDS: 2 A-tiles x 32768 halves = 128 KiB (tile0 = hidden, tile1 = input)
  extern __shared__ _Float16 sA[];

  const int blk   = blockIdx.x;
  const int layer = blk >> 6;             // 0,1,2
  const int nb    = blk & 63;
  const int ug    = nb >> 3;              // unit group 0..7 (64 units each)
  const int bt    = nb & 7;               // batch tile 0..7 (32 rows each)
  const int u0    = ug * 64;
  const int tid   = threadIdx.x;
  const int lane  = tid & 63;
  const int wave  = tid >> 6;
  const int lane32 = lane & 31;
  const int hi2   = lane >> 5;

  const int r64  = wave * 32 + lane32;    // block-local gate row 0..255
  const int tg   = r64 & 3;               // gate type i,f,g,o
  const int uu   = r64 >> 2;              // unit within block 0..63
  const int grow = tg * HID + u0 + uu;    // global gate row 0..2047

  const float* Wih = (layer == 0) ? Wih0 : (layer == 1 ? Wih1 : Wih2);
  const float* Whh = (layer == 0) ? Whh0 : (layer == 1 ? Whh1 : Whh2);
  const float* bih = (layer == 0) ? bih0 : (layer == 1 ? bih1 : bih2);
  const float* bhh = (layer == 0) ? bhh0 : (layer == 1 ? bhh1 : bhh2);

  // ---- weights into registers (one-time): wave owns gate rows [wave*32, wave*32+32) ----
  // per lane: B-fragment chunks for k = (2*ks + hi2)*8 .. +8, ks = 0..31, both matrices
  half8 wih[32], whh[32];
  #pragma unroll
  for (int ks = 0; ks < 32; ++ks) {
    const int col = (ks * 2 + hi2) * 8;
    whh[ks] = cvt8(Whh + (size_t)grow * 512 + col);
    if (layer > 0) {
      wih[ks] = cvt8(Wih + (size_t)grow * 512 + col);
    } else {
      half8 z = {};
      wih[ks] = z;
    }
  }

  const float bias_c = bih[grow] + bhh[grow];
  float w0_c = 0.f, w1_c = 0.f;
  if (layer == 0) { w0_c = Wih0[grow * 2]; w1_c = Wih0[grow * 2 + 1]; }

  // c-state: 16 batch rows per lane (4x redundant across gate-type lanes)
  float cst[16];
  #pragma unroll
  for (int r = 0; r < 16; ++r) cst[r] = 0.f;

  _Float16* hws = (_Float16*)ws;   // 6 arrays: [layer][parity] of HARR halves
  const half8* ap = (const half8*)sA;

  cg::grid_group grid = cg::this_grid();

  for (int u = 0; u < SEQ + 2; ++u) {
    const int t = u - layer;
    if (t >= 0 && t < SEQ) {
      const int pr = (u + 1) & 1;   // read parity
      const int pw = u & 1;         // write parity

      // ---- stage A-tiles (verbatim fragment-order copies, 64 KiB each) ----
      {
        const _Float16* srcH = hws + (size_t)(layer * 2 + pr) * HARR + bt * TILEH;
        #pragma unroll
        for (int j = 0; j < 8; ++j) {
          const int jj = j * 8 + wave;
          stage16(srcH + jj * 512 + lane * 8, sA + jj * 512);
        }
        if (layer > 0) {
          const _Float16* srcX = hws + (size_t)((layer - 1) * 2 + pr) * HARR + bt * TILEH;
          #pragma unroll
          for (int j = 0; j < 8; ++j) {
            const int jj = j * 8 + wave;
            stage16(srcX + jj * 512 + lane * 8, sA + TILEH + jj * 512);
          }
        }
      }
      __syncthreads();   // drains vmcnt (global_load_lds) + lgkm before LDS reads

      f32x16 acc0, acc1, acc2, acc3;
      #pragma unroll
      for (int r = 0; r < 16; ++r) { acc0[r] = 0.f; acc1[r] = 0.f; acc2[r] = 0.f; acc3[r] = 0.f; }

      // hidden GEMM from tile 0 (B from registers)
      #pragma unroll
      for (int ks = 0; ks < 32; ++ks) {
        const int gi = ks * 2 + hi2;
        half8 av = ap[(gi * 2 + 0) * 32 + lane32];
        half8 lv = ap[(gi * 2 + 1) * 32 + lane32];
        acc0 = __builtin_amdgcn_mfma_f32_32x32x16_f16(av, whh[ks], acc0, 0, 0, 0);
        acc1 = __builtin_amdgcn_mfma_f32_32x32x16_f16(lv, whh[ks], acc1, 0, 0, 0);
      }
      if (layer > 0) {   // input GEMM from tile 1
        #pragma unroll
        for (int ks = 0; ks < 32; ++ks) {
          const int gi = ks * 2 + hi2;
          half8 av = ap[4096 + (gi * 2 + 0) * 32 + lane32];
          half8 lv = ap[4096 + (gi * 2 + 1) * 32 + lane32];
          acc2 = __builtin_amdgcn_mfma_f32_32x32x16_f16(av, wih[ks], acc2, 0, 0, 0);
          acc3 = __builtin_amdgcn_mfma_f32_32x32x16_f16(lv, wih[ks], acc3, 0, 0, 0);
        }
      }

      // ---- elementwise ----
      float gv[16];
      #pragma unroll
      for (int r = 0; r < 16; ++r) {
        float g = acc0[r] + acc1[r] + bias_c;
        if (layer > 0) g += acc2[r] + acc3[r];
        if (layer == 0) {
          const int m = bt * 32 + (r & 3) + 8 * (r >> 2) + 4 * hi2;
          const float2* xp = (const float2*)tracks;
          const float2 xv = xp[(size_t)m * SEQ + t];
          g += w0_c * xv.x + w1_c * xv.y;
        }
        gv[r] = g;
      }

      // gather i,f,g,o for this lane's unit: cols (c&28)+0..3 in same half-wave
      const int sb = (lane & 32) | (lane32 & 28);
      _Float16* wr = hws + (size_t)(layer * 2 + pw) * HARR;
      const int gran = (u0 + uu) >> 3;
      const int k7   = (u0 + uu) & 7;
      #pragma unroll
      for (int r = 0; r < 16; ++r) {
        const float gi_ = __shfl(gv[r], sb,     64);
        const float gf_ = __shfl(gv[r], sb | 1, 64);
        const float gg_ = __shfl(gv[r], sb | 2, 64);
        const float go_ = __shfl(gv[r], sb | 3, 64);
        const float iv = sigf(gi_);
        const float fv = sigf(gf_);
        const float gn = tanhf(gg_);
        const float ov = sigf(go_);
        const float cn = fv * cst[r] + iv * gn;
        cst[r] = cn;
        const float hn = ov * tanhf(cn);
        if ((r >> 2) == tg) {  // each gate-type lane writes its batch-row quad
          const int m_local = (r & 3) + 8 * tg + 4 * hi2;
          const _Float16 hif = (_Float16)hn;
          const _Float16 lof = (_Float16)(hn - (float)hif);
          const int off = (((bt * 64 + gran) * 2 + 0) * 32 + m_local) * 8 + k7;
          wr[off]       = hif;
          wr[off + 256] = lof;   // hilo=1 chunk is +32*8 halves
        }
      }
    }
    grid.sync();
  }

  // ---- output head: out[b][p] = elu(h2_final[b]) . Wpred[p] + bpred[p] ----
  // final h2 written at tick 513 -> parity 1
  const int gw = blk * 8 + wave;
  if (gw < BATCH * 4) {
    const int b = gw >> 2;
    const int p = gw & 3;
    const _Float16* Hf = hws + (size_t)(2 * 2 + 1) * HARR;
    const int k = lane * 8;          // gran = lane
    const int offh = ((((b >> 5) * 64 + lane) * 2 + 0) * 32 + (b & 31)) * 8;
    float a = 0.f;
    #pragma unroll
    for (int j = 0; j < 8; ++j) {
      const float hv = (float)Hf[offh + j] + (float)Hf[offh + 256 + j];
      const float e = hv > 0.f ? hv : expm1f(hv);
      a += e * Wpred[p * HID + k + j];
    }
    #pragma unroll
    for (int off = 32; off > 0; off >>= 1) a += __shfl_down(a, off, 64);
    if (lane == 0) out[b * 4 + p] = a + bpred[p];
  }
}

extern "C" void kernel_launch(void* const* d_in, const int* in_sizes, int n_in,
                              void* d_out, int out_size, void* d_ws, size_t ws_size,
                              hipStream_t stream) {
  const float* tracks = (const float*)d_in[0];
  const float* Wih0  = (const float*)d_in[1];
  const float* bih0  = (const float*)d_in[2];
  const float* Whh0  = (const float*)d_in[3];
  const float* bhh0  = (const float*)d_in[4];
  const float* Wih1  = (const float*)d_in[5];
  const float* bih1  = (const float*)d_in[6];
  const float* Whh1  = (const float*)d_in[7];
  const float* bhh1  = (const float*)d_in[8];
  const float* Wih2  = (const float*)d_in[9];
  const float* bih2  = (const float*)d_in[10];
  const float* Whh2  = (const float*)d_in[11];
  const float* bhh2  = (const float*)d_in[12];
  const float* Wpred = (const float*)d_in[13];
  const float* bpred = (const float*)d_in[14];
  float* out = (float*)d_out;
  unsigned short* ws = (unsigned short*)d_ws;

  // allow 128 KiB dynamic LDS (host-side attribute, idempotent, capture-safe)
  hipFuncSetAttribute(reinterpret_cast<const void*>(lstm3_persistent),
                      hipFuncAttributeMaxDynamicSharedMemorySize, 131072);

  // zero the h double-buffers every call (recurrence starts from h=0 on every replay)
  hipMemsetAsync(d_ws, 0, (size_t)6 * HARR * sizeof(unsigned short), stream);

  void* args[] = { &tracks, &Wih0, &bih0, &Whh0, &bhh0,
                   &Wih1, &bih1, &Whh1, &bhh1,
                   &Wih2, &bih2, &Whh2, &bhh2,
                   &Wpred, &bpred, &out, &ws };
  hipLaunchCooperativeKernel(reinterpret_cast<void*>(lstm3_persistent),
                             dim3(NBLK), dim3(NTHR), args, 131072, stream);
}

// Round 4
// 16458.072 us; speedup vs baseline: 1.4210x; 1.4210x over previous
//
#include <hip/hip_runtime.h>
#include <hip/hip_cooperative_groups.h>

#define HID   512
#define BATCH 256
#define SEQ   512
#define NBLK  192
#define NTHR  512
#define HARR  262144   // halves per (layer,parity) h array = 8 tiles x TILEH
#define TILEH 32768    // halves per 32-row batch tile (64 KiB)

typedef __attribute__((ext_vector_type(8))) _Float16 half8;
typedef __attribute__((ext_vector_type(16))) float f32x16;

typedef __attribute__((address_space(1))) const unsigned int kGlobU32;
typedef __attribute__((address_space(3))) unsigned int kLdsU32;

__device__ __forceinline__ float sigf(float x) { return 1.0f / (1.0f + __expf(-x)); }
// fast tanh via hw exp; saturates correctly at +/-inf
__device__ __forceinline__ float tanhf_(float x) { return 1.0f - 2.0f / (__expf(2.0f * x) + 1.0f); }

__device__ __forceinline__ half8 cvt8(const float* p) {
  const float4 a = ((const float4*)p)[0];
  const float4 b = ((const float4*)p)[1];
  half8 r;
  r[0] = (_Float16)a.x; r[1] = (_Float16)a.y; r[2] = (_Float16)a.z; r[3] = (_Float16)a.w;
  r[4] = (_Float16)b.x; r[5] = (_Float16)b.y; r[6] = (_Float16)b.z; r[7] = (_Float16)b.w;
  return r;
}

// async global->LDS, 16 B per lane; lds dest = wave-uniform base + lane*16 (HW rule)
__device__ __forceinline__ void stage16(const _Float16* g, _Float16* l) {
  __builtin_amdgcn_global_load_lds((kGlobU32*)g, (kLdsU32*)l, 16, 0, 0);
}

__global__ __launch_bounds__(NTHR, 1)   // 1 block/CU (128KiB LDS); full 512-reg file, no spill
void lstm3_persistent(const float* __restrict__ tracks,
                      const float* __restrict__ Wih0, const float* __restrict__ bih0,
                      const float* __restrict__ Whh0, const float* __restrict__ bhh0,
                      const float* __restrict__ Wih1, const float* __restrict__ bih1,
                      const float* __restrict__ Whh1, const float* __restrict__ bhh1,
                      const float* __restrict__ Wih2, const float* __restrict__ bih2,
                      const float* __restrict__ Whh2, const float* __restrict__ bhh2,
                      const float* __restrict__ Wpred, const float* __restrict__ bpred,
                      float* __restrict__ out, unsigned short* __restrict__ ws,
                      int* __restrict__ prog)
{
  // dynamic LDS: 2 A-tiles x 32768 halves = 128 KiB (tile0 = hidden, tile1 = input)
  extern __shared__ _Float16 sA[];

  const int blk   = blockIdx.x;
  // bt in low bits: all 24 blocks sharing a batch-tile land on one XCD (perf-only)
  const int bt    = blk & 7;              // batch tile 0..7 (32 rows each)
  const int rest  = blk >> 3;             // 0..23
  const int layer = rest >> 3;            // 0,1,2
  const int ug    = rest & 7;             // unit group 0..7 (64 units each)
  const int u0    = ug * 64;
  const int tid   = threadIdx.x;
  const int lane  = tid & 63;
  const int wave  = tid >> 6;
  const int lane32 = lane & 31;
  const int hi2   = lane >> 5;

  const int r64  = wave * 32 + lane32;    // block-local gate row 0..255
  const int tg   = r64 & 3;               // gate type i,f,g,o
  const int uu   = r64 >> 2;              // unit within block 0..63
  const int grow = tg * HID + u0 + uu;    // global gate row 0..2047

  const float* Wih = (layer == 0) ? Wih0 : (layer == 1 ? Wih1 : Wih2);
  const float* Whh = (layer == 0) ? Whh0 : (layer == 1 ? Whh1 : Whh2);
  const float* bih = (layer == 0) ? bih0 : (layer == 1 ? bih1 : bih2);
  const float* bhh = (layer == 0) ? bhh0 : (layer == 1 ? bhh1 : bhh2);

  // ---- weights into registers (one-time): wave owns gate rows [wave*32, wave*32+32) ----
  half8 wih[32], whh[32];
  #pragma unroll
  for (int ks = 0; ks < 32; ++ks) {
    const int col = (ks * 2 + hi2) * 8;
    whh[ks] = cvt8(Whh + (size_t)grow * 512 + col);
    if (layer > 0) {
      wih[ks] = cvt8(Wih + (size_t)grow * 512 + col);
    } else {
      half8 z = {};
      wih[ks] = z;
    }
  }

  const float bias_c = bih[grow] + bhh[grow];
  float w0_c = 0.f, w1_c = 0.f;
  if (layer == 0) { w0_c = Wih0[grow * 2]; w1_c = Wih0[grow * 2 + 1]; }

  float cst[16];
  #pragma unroll
  for (int r = 0; r < 16; ++r) cst[r] = 0.f;

  _Float16* hws = (_Float16*)ws;   // 6 arrays: [layer*2+parity] of HARR halves
  const half8* ap = (const half8*)sA;

  for (int t = 0; t < SEQ; ++t) {
    const int pr = (t + 1) & 1;   // parity of t-1 (own-layer h read)
    const int pw = t & 1;         // parity of t   (write; also x read from layer-1)

    // layer-0 input: independent of flags -> issue before the wait
    float2 xv[16];
    if (layer == 0) {
      const float2* xp = (const float2*)tracks;
      #pragma unroll
      for (int r = 0; r < 16; ++r) {
        const int m = bt * 32 + (r & 3) + 8 * (r >> 2) + 4 * hi2;
        xv[r] = xp[(size_t)m * SEQ + t];
      }
    }

    // ---- distributed sync: wait for producers (and anti-dep readers) ----
    if (tid == 0) {
      if (layer > 0)   // input ready: layer-1 finished t
        while (__hip_atomic_load(&prog[(layer - 1) * 8 + bt], __ATOMIC_RELAXED,
                                 __HIP_MEMORY_SCOPE_AGENT) < 8 * (t + 1))
          __builtin_amdgcn_s_sleep(1);
      if (t > 0)       // own-layer h ready: all 8 ug finished t-1
        while (__hip_atomic_load(&prog[layer * 8 + bt], __ATOMIC_RELAXED,
                                 __HIP_MEMORY_SCOPE_AGENT) < 8 * t)
          __builtin_amdgcn_s_sleep(1);
      if (layer < 2 && t >= 2)   // anti-dep: layer+1 finished reading buffer we overwrite
        while (__hip_atomic_load(&prog[(layer + 1) * 8 + bt], __ATOMIC_RELAXED,
                                 __HIP_MEMORY_SCOPE_AGENT) < 8 * (t - 1))
          __builtin_amdgcn_s_sleep(1);
      __builtin_amdgcn_fence(__ATOMIC_ACQUIRE, "agent");   // one inv per tick
    }
    __syncthreads();

    // ---- stage A-tiles into LDS ----
    if (t > 0) {
      const _Float16* srcH = hws + (size_t)(layer * 2 + pr) * HARR + bt * TILEH;
      #pragma unroll
      for (int j = 0; j < 8; ++j) {
        const int jj = j * 8 + wave;
        stage16(srcH + jj * 512 + lane * 8, sA + jj * 512);
      }
    }
    if (layer > 0) {
      const _Float16* srcX = hws + (size_t)((layer - 1) * 2 + pw) * HARR + bt * TILEH;
      #pragma unroll
      for (int j = 0; j < 8; ++j) {
        const int jj = j * 8 + wave;
        stage16(srcX + jj * 512 + lane * 8, sA + TILEH + jj * 512);
      }
    }
    __syncthreads();   // drains vmcnt (global_load_lds) before LDS reads

    f32x16 acc0, acc1, acc2, acc3;
    #pragma unroll
    for (int r = 0; r < 16; ++r) { acc0[r] = 0.f; acc1[r] = 0.f; acc2[r] = 0.f; acc3[r] = 0.f; }

    if (t > 0) {   // hidden GEMM from tile 0 (h[-1] = 0 -> skip at t=0)
      #pragma unroll
      for (int ks = 0; ks < 32; ++ks) {
        const int gi = ks * 2 + hi2;
        half8 av = ap[(gi * 2 + 0) * 32 + lane32];
        half8 lv = ap[(gi * 2 + 1) * 32 + lane32];
        acc0 = __builtin_amdgcn_mfma_f32_32x32x16_f16(av, whh[ks], acc0, 0, 0, 0);
        acc1 = __builtin_amdgcn_mfma_f32_32x32x16_f16(lv, whh[ks], acc1, 0, 0, 0);
      }
    }
    if (layer > 0) {   // input GEMM from tile 1
      #pragma unroll
      for (int ks = 0; ks < 32; ++ks) {
        const int gi = ks * 2 + hi2;
        half8 av = ap[4096 + (gi * 2 + 0) * 32 + lane32];
        half8 lv = ap[4096 + (gi * 2 + 1) * 32 + lane32];
        acc2 = __builtin_amdgcn_mfma_f32_32x32x16_f16(av, wih[ks], acc2, 0, 0, 0);
        acc3 = __builtin_amdgcn_mfma_f32_32x32x16_f16(lv, wih[ks], acc3, 0, 0, 0);
      }
    }

    // ---- elementwise ----
    float gv[16];
    #pragma unroll
    for (int r = 0; r < 16; ++r) {
      float g = acc0[r] + acc1[r] + bias_c;
      if (layer > 0) g += acc2[r] + acc3[r];
      if (layer == 0) g += w0_c * xv[r].x + w1_c * xv[r].y;
      gv[r] = g;
    }

    const int sb = (lane & 32) | (lane32 & 28);
    _Float16* wr = hws + (size_t)(layer * 2 + pw) * HARR;
    const int gran = (u0 + uu) >> 3;
    const int k7   = (u0 + uu) & 7;
    #pragma unroll
    for (int r = 0; r < 16; ++r) {
      const float gi_ = __shfl(gv[r], sb,     64);
      const float gf_ = __shfl(gv[r], sb | 1, 64);
      const float gg_ = __shfl(gv[r], sb | 2, 64);
      const float go_ = __shfl(gv[r], sb | 3, 64);
      const float iv = sigf(gi_);
      const float fv = sigf(gf_);
      const float gn = tanhf_(gg_);
      const float ov = sigf(go_);
      const float cn = fv * cst[r] + iv * gn;
      cst[r] = cn;
      const float hn = ov * tanhf_(cn);
      if ((r >> 2) == tg) {
        const int m_local = (r & 3) + 8 * tg + 4 * hi2;
        const _Float16 hif = (_Float16)hn;
        const _Float16 lof = (_Float16)(hn - (float)hif);
        const int off = (((bt * 64 + gran) * 2 + 0) * 32 + m_local) * 8 + k7;
        wr[off]       = hif;
        wr[off + 256] = lof;
      }
    }

    // ---- publish: all block writes done -> one release RMW ----
    __syncthreads();   // waits each wave's vmcnt; all stores in L2
    if (tid == 0) {
      __hip_atomic_fetch_add(&prog[layer * 8 + bt], 1, __ATOMIC_RELEASE,
                             __HIP_MEMORY_SCOPE_AGENT);   // wbl2 + RMW
    }
  }

  // ---- final sync: all layer-2 tiles at t=511 published ----
  if (tid == 0) {
    #pragma unroll
    for (int b = 0; b < 8; ++b)
      while (__hip_atomic_load(&prog[16 + b], __ATOMIC_RELAXED,
                               __HIP_MEMORY_SCOPE_AGENT) < 8 * SEQ)
        __builtin_amdgcn_s_sleep(1);
    __builtin_amdgcn_fence(__ATOMIC_ACQUIRE, "agent");
  }
  __syncthreads();

  // ---- output head: out[b][p] = elu(h2_final[b]) . Wpred[p] + bpred[p] ----
  // final h2 at parity 511&1 = 1
  const int gw = blk * 8 + wave;
  if (gw < BATCH * 4) {
    const int b = gw >> 2;
    const int p = gw & 3;
    const _Float16* Hf = hws + (size_t)(2 * 2 + 1) * HARR;
    const int k = lane * 8;          // gran = lane
    const int offh = ((((b >> 5) * 64 + lane) * 2 + 0) * 32 + (b & 31)) * 8;
    float a = 0.f;
    #pragma unroll
    for (int j = 0; j < 8; ++j) {
      const float hv = (float)Hf[offh + j] + (float)Hf[offh + 256 + j];
      const float e = hv > 0.f ? hv : expm1f(hv);
      a += e * Wpred[p * HID + k + j];
    }
    #pragma unroll
    for (int off = 32; off > 0; off >>= 1) a += __shfl_down(a, off, 64);
    if (lane == 0) out[b * 4 + p] = a + bpred[p];
  }
}

extern "C" void kernel_launch(void* const* d_in, const int* in_sizes, int n_in,
                              void* d_out, int out_size, void* d_ws, size_t ws_size,
                              hipStream_t stream) {
  const float* tracks = (const float*)d_in[0];
  const float* Wih0  = (const float*)d_in[1];
  const float* bih0  = (const float*)d_in[2];
  const float* Whh0  = (const float*)d_in[3];
  const float* bhh0  = (const float*)d_in[4];
  const float* Wih1  = (const float*)d_in[5];
  const float* bih1  = (const float*)d_in[6];
  const float* Whh1  = (const float*)d_in[7];
  const float* bhh1  = (const float*)d_in[8];
  const float* Wih2  = (const float*)d_in[9];
  const float* bih2  = (const float*)d_in[10];
  const float* Whh2  = (const float*)d_in[11];
  const float* bhh2  = (const float*)d_in[12];
  const float* Wpred = (const float*)d_in[13];
  const float* bpred = (const float*)d_in[14];
  float* out = (float*)d_out;
  unsigned short* ws = (unsigned short*)d_ws;
  int* prog = (int*)((char*)d_ws + (size_t)6 * HARR * 2);   // 24 counters after h arrays

  hipFuncSetAttribute(reinterpret_cast<const void*>(lstm3_persistent),
                      hipFuncAttributeMaxDynamicSharedMemorySize, 131072);

  // zero ONLY the progress counters each call (h needs no init: t=0 skips hidden read)
  hipMemsetAsync(prog, 0, 32 * sizeof(int), stream);

  void* args[] = { &tracks, &Wih0, &bih0, &Whh0, &bhh0,
                   &Wih1, &bih1, &Whh1, &bhh1,
                   &Wih2, &bih2, &Whh2, &bhh2,
                   &Wpred, &bpred, &out, &ws, &prog };
  hipLaunchCooperativeKernel(reinterpret_cast<void*>(lstm3_persistent),
                             dim3(NBLK), dim3(NTHR), args, 131072, stream);
}

// Round 5
// 9638.824 us; speedup vs baseline: 2.4263x; 1.7075x over previous
//
#include <hip/hip_runtime.h>

#define HID   512
#define BATCH 256
#define SEQ   512
#define NBLK  192
#define NTHR  512
#define HARR  262144   // halves per (layer,parity): hi[16ks][16rtg][4ko][16r][8] + lo
#define HLO   131072   // lo-part offset (halves)

typedef __attribute__((ext_vector_type(8))) _Float16 half8;
typedef __attribute__((ext_vector_type(4))) float f32x4;

typedef __attribute__((address_space(1))) const unsigned int kGlobU32;
typedef __attribute__((address_space(3))) unsigned int kLdsU32;

__device__ __forceinline__ float sigf(float x) { return 1.0f / (1.0f + __expf(-x)); }
__device__ __forceinline__ float tanhf_(float x) { return 1.0f - 2.0f / (__expf(2.0f * x) + 1.0f); }

__device__ __forceinline__ half8 cvt8(const float* p) {
  const float4 a = ((const float4*)p)[0];
  const float4 b = ((const float4*)p)[1];
  half8 r;
  r[0] = (_Float16)a.x; r[1] = (_Float16)a.y; r[2] = (_Float16)a.z; r[3] = (_Float16)a.w;
  r[4] = (_Float16)b.x; r[5] = (_Float16)b.y; r[6] = (_Float16)b.z; r[7] = (_Float16)b.w;
  return r;
}

// wave w stages its 8 slabs (1 KiB each) of a 64 KiB A-half into LDS buffer BUFB
#define STAGE(SRC, BUFB) do { \
  _Pragma("unroll") \
  for (int q = 0; q < 8; ++q) { \
    const int s = wave * 8 + q; \
    const _Float16* gsrc = (SRC) + ((s >> 2) * 16 + bt * 4 + (s & 3)) * 512 + lane * 8; \
    __builtin_amdgcn_global_load_lds((kGlobU32*)gsrc, \
        (kLdsU32*)(sA + (BUFB) * 32768 + s * 512), 16, 0, 0); \
  } } while (0)

// one GEMM pass over a staged A-half: 16 k-steps x 4 row-tiles, B from registers
#define MFMA_PASS(WARR, BUFB) do { \
  _Pragma("unroll") \
  for (int ks = 0; ks < 16; ++ks) { \
    _Pragma("unroll") \
    for (int rt = 0; rt < 4; ++rt) { \
      const half8 av = *(const half8*)(sA + (BUFB) * 32768 + (ks * 4 + rt) * 512 + lane * 8); \
      acc[rt] = __builtin_amdgcn_mfma_f32_16x16x32_f16(av, WARR[ks], acc[rt], 0, 0, 0); \
    } } } while (0)

#define VMCNT8 asm volatile("s_waitcnt vmcnt(8)" ::: "memory")
#define VMCNT0 asm volatile("s_waitcnt vmcnt(0)" ::: "memory")
#define SBAR() __builtin_amdgcn_s_barrier()

__global__ __launch_bounds__(NTHR, 2)   // 8 waves = 2/SIMD -> 256-VGPR cap, MUST fit
void lstm3_persistent(const float* __restrict__ tracks,
                      const float* __restrict__ Wih0, const float* __restrict__ bih0,
                      const float* __restrict__ Whh0, const float* __restrict__ bhh0,
                      const float* __restrict__ Wih1, const float* __restrict__ bih1,
                      const float* __restrict__ Whh1, const float* __restrict__ bhh1,
                      const float* __restrict__ Wih2, const float* __restrict__ bih2,
                      const float* __restrict__ Whh2, const float* __restrict__ bhh2,
                      const float* __restrict__ Wpred, const float* __restrict__ bpred,
                      float* __restrict__ out, unsigned short* __restrict__ ws,
                      int* __restrict__ prog)
{
  extern __shared__ _Float16 sA[];   // 2 x 64 KiB A-staging buffers

  const int blk  = blockIdx.x;
  const int bt   = (blk >> 1) & 3;            // batch tile (64 rows); XCD-pair local
  const int rr   = (blk & 1) * 24 + (blk >> 3);  // 0..47
  const int layer = rr >> 4;                  // 0,1,2
  const int ug    = rr & 15;                  // unit group (32 units)
  const int u0    = ug * 32;
  const int tid  = threadIdx.x;
  const int lane = tid & 63;
  const int wave = tid >> 6;
  const int c    = lane & 15;                 // gate col within wave
  const int kod  = lane >> 4;                 // k-octet / D-row group
  const int tg   = c & 3;                     // gate type i,f,g,o
  const int usub = c >> 2;
  const int unit = u0 + wave * 4 + usub;      // this lane's hidden unit
  const int grow = tg * HID + unit;           // global gate row

  const float* Wih = (layer == 0) ? Wih0 : (layer == 1 ? Wih1 : Wih2);
  const float* Whh = (layer == 0) ? Whh0 : (layer == 1 ? Whh1 : Whh2);
  const float* bih = (layer == 0) ? bih0 : (layer == 1 ? bih1 : bih2);
  const float* bhh = (layer == 0) ? bhh0 : (layer == 1 ? bhh1 : bhh2);

  // ---- weights into registers: 16 cols/wave -> 64 VGPR per matrix ----
  half8 whh_r[16], wih_r[16];
  #pragma unroll
  for (int ks = 0; ks < 16; ++ks) {
    const int col = ks * 32 + kod * 8;
    whh_r[ks] = cvt8(Whh + (size_t)grow * 512 + col);
    if (layer > 0) wih_r[ks] = cvt8(Wih + (size_t)grow * 512 + col);
    else { half8 z = {}; wih_r[ks] = z; }
  }

  const float bias_c = bih[grow] + bhh[grow];
  float w0_c = 0.f, w1_c = 0.f;
  if (layer == 0) { w0_c = Wih0[grow * 2]; w1_c = Wih0[grow * 2 + 1]; }

  float cst[16];
  #pragma unroll
  for (int r = 0; r < 16; ++r) cst[r] = 0.f;

  _Float16* hws = (_Float16*)ws;
  const int sb = (lane & 48) | (c & 12);      // shuffle base: 4 gates of my unit-slot
  const int myflag   = (layer * 4 + bt) * 32;
  const int prodflag = ((layer - 1) * 4 + bt) * 32;
  const int consflag = ((layer + 1) * 4 + bt) * 32;

  for (int t = 0; t < SEQ; ++t) {
    const int pr = (t + 1) & 1;
    const int pw = t & 1;

    // ---- distributed sync (R4 protocol, 16 blocks per counter) ----
    if (tid == 0) {
      if (layer > 0)
        while (__hip_atomic_load(&prog[prodflag], __ATOMIC_RELAXED,
                                 __HIP_MEMORY_SCOPE_AGENT) < 16 * (t + 1))
          __builtin_amdgcn_s_sleep(1);
      if (t > 0)
        while (__hip_atomic_load(&prog[myflag], __ATOMIC_RELAXED,
                                 __HIP_MEMORY_SCOPE_AGENT) < 16 * t)
          __builtin_amdgcn_s_sleep(1);
      if (layer < 2 && t >= 2)
        while (__hip_atomic_load(&prog[consflag], __ATOMIC_RELAXED,
                                 __HIP_MEMORY_SCOPE_AGENT) < 16 * (t - 1))
          __builtin_amdgcn_s_sleep(1);
      __builtin_amdgcn_fence(__ATOMIC_ACQUIRE, "agent");
    }
    __syncthreads();

    const _Float16* Hs = hws + (size_t)(layer * 2 + pr) * HARR;
    const _Float16* Xs = (layer > 0) ? hws + (size_t)((layer - 1) * 2 + pw) * HARR : (const _Float16*)0;
    const bool doH = (t > 0);
    const bool doX = (layer > 0);

    f32x4 acc[4];
    #pragma unroll
    for (int rt = 0; rt < 4; ++rt) { acc[rt][0]=0.f; acc[rt][1]=0.f; acc[rt][2]=0.f; acc[rt][3]=0.f; }

    // ---- pipelined passes: stage(i+2) overlaps mfma(i); vmcnt counted, never 0 mid-loop ----
    if (doH && doX) {
      STAGE(Hs, 0); STAGE(Hs + HLO, 1); VMCNT8; SBAR();
      MFMA_PASS(whh_r, 0); SBAR(); STAGE(Xs, 0);       VMCNT8; SBAR();
      MFMA_PASS(whh_r, 1); SBAR(); STAGE(Xs + HLO, 1); VMCNT8; SBAR();
      MFMA_PASS(wih_r, 0); SBAR();                     VMCNT0; SBAR();
      MFMA_PASS(wih_r, 1);
    } else if (doH) {
      STAGE(Hs, 0); STAGE(Hs + HLO, 1); VMCNT8; SBAR();
      MFMA_PASS(whh_r, 0); SBAR();                     VMCNT0; SBAR();
      MFMA_PASS(whh_r, 1);
    } else if (doX) {
      STAGE(Xs, 0); STAGE(Xs + HLO, 1); VMCNT8; SBAR();
      MFMA_PASS(wih_r, 0); SBAR();                     VMCNT0; SBAR();
      MFMA_PASS(wih_r, 1);
    }

    // ---- elementwise ----
    _Float16* wr = hws + (size_t)(layer * 2 + pw) * HARR;
    #pragma unroll
    for (int rt = 0; rt < 4; ++rt) {
      float2 xv[4];
      if (layer == 0) {
        #pragma unroll
        for (int rg = 0; rg < 4; ++rg) {
          const int m = bt * 64 + rt * 16 + kod * 4 + rg;
          xv[rg] = ((const float2*)tracks)[(size_t)m * SEQ + t];
        }
      }
      #pragma unroll
      for (int rg = 0; rg < 4; ++rg) {
        float g = acc[rt][rg] + bias_c;
        if (layer == 0) g += w0_c * xv[rg].x + w1_c * xv[rg].y;
        const float gi_ = __shfl(g, sb | 0, 64);
        const float gf_ = __shfl(g, sb | 1, 64);
        const float gg_ = __shfl(g, sb | 2, 64);
        const float go_ = __shfl(g, sb | 3, 64);
        const float iv = sigf(gi_);
        const float fv = sigf(gf_);
        const float gn = tanhf_(gg_);
        const float ov = sigf(go_);
        const float cn = fv * cst[rt * 4 + rg] + iv * gn;
        cst[rt * 4 + rg] = cn;
        const float hn = ov * tanhf_(cn);
        if (tg == 0) {   // one gate-group writes h for its unit
          const _Float16 hif = (_Float16)hn;
          const _Float16 lof = (_Float16)(hn - (float)hif);
          const int r16 = kod * 4 + rg;
          const size_t off = ((size_t)((unit >> 5) * 16 + bt * 4 + rt) * 4
                              + ((unit >> 3) & 3)) * 128 + r16 * 8 + (unit & 7);
          wr[off]       = hif;
          wr[off + HLO] = lof;
        }
      }
    }

    // ---- publish ----
    __syncthreads();   // per-wave vmcnt drain + barrier: all h-stores in L2
    if (tid == 0)
      __hip_atomic_fetch_add(&prog[myflag], 1, __ATOMIC_RELEASE,
                             __HIP_MEMORY_SCOPE_AGENT);
  }

  // ---- final sync: all layer-2 tiles done ----
  if (tid == 0) {
    #pragma unroll
    for (int b = 0; b < 4; ++b)
      while (__hip_atomic_load(&prog[(8 + b) * 32], __ATOMIC_RELAXED,
                               __HIP_MEMORY_SCOPE_AGENT) < 16 * SEQ)
        __builtin_amdgcn_s_sleep(1);
    __builtin_amdgcn_fence(__ATOMIC_ACQUIRE, "agent");
  }
  __syncthreads();

  // ---- output head: out[b][p] = elu(h2_final[b]) . Wpred[p] + bpred[p] ----
  const int gw = blk * 8 + wave;
  if (gw < BATCH * 4) {
    const int b = gw >> 2;
    const int p = gw & 3;
    const _Float16* Hf = hws + (size_t)5 * HARR;   // layer 2, parity 1 (t=511)
    const size_t base = ((size_t)((lane >> 2) * 16 + (b >> 4)) * 4 + (lane & 3)) * 128
                        + (size_t)(b & 15) * 8;
    const half8 hh = *(const half8*)(Hf + base);
    const half8 hl = *(const half8*)(Hf + HLO + base);
    float a = 0.f;
    #pragma unroll
    for (int j = 0; j < 8; ++j) {
      const float hv = (float)hh[j] + (float)hl[j];
      const float e = hv > 0.f ? hv : expm1f(hv);
      a += e * Wpred[p * HID + lane * 8 + j];
    }
    #pragma unroll
    for (int off = 32; off > 0; off >>= 1) a += __shfl_down(a, off, 64);
    if (lane == 0) out[b * 4 + p] = a + bpred[p];
  }
}

extern "C" void kernel_launch(void* const* d_in, const int* in_sizes, int n_in,
                              void* d_out, int out_size, void* d_ws, size_t ws_size,
                              hipStream_t stream) {
  const float* tracks = (const float*)d_in[0];
  const float* Wih0  = (const float*)d_in[1];
  const float* bih0  = (const float*)d_in[2];
  const float* Whh0  = (const float*)d_in[3];
  const float* bhh0  = (const float*)d_in[4];
  const float* Wih1  = (const float*)d_in[5];
  const float* bih1  = (const float*)d_in[6];
  const float* Whh1  = (const float*)d_in[7];
  const float* bhh1  = (const float*)d_in[8];
  const float* Wih2  = (const float*)d_in[9];
  const float* bih2  = (const float*)d_in[10];
  const float* Whh2  = (const float*)d_in[11];
  const float* bhh2  = (const float*)d_in[12];
  const float* Wpred = (const float*)d_in[13];
  const float* bpred = (const float*)d_in[14];
  float* out = (float*)d_out;
  unsigned short* ws = (unsigned short*)d_ws;
  int* prog = (int*)((char*)d_ws + (size_t)6 * HARR * 2);   // 12 padded counters

  hipFuncSetAttribute(reinterpret_cast<const void*>(lstm3_persistent),
                      hipFuncAttributeMaxDynamicSharedMemorySize, 131072);

  // zero only the progress counters (h needs no init: t=0 skips the hidden pass)
  hipMemsetAsync(prog, 0, 12 * 32 * sizeof(int), stream);

  void* args[] = { &tracks, &Wih0, &bih0, &Whh0, &bhh0,
                   &Wih1, &bih1, &Whh1, &bhh1,
                   &Wih2, &bih2, &Whh2, &bhh2,
                   &Wpred, &bpred, &out, &ws, &prog };
  hipLaunchCooperativeKernel(reinterpret_cast<void*>(lstm3_persistent),
                             dim3(NBLK), dim3(NTHR), args, 131072, stream);
}

// Round 6
// 8277.542 us; speedup vs baseline: 2.8254x; 1.1645x over previous
//
#include <hip/hip_runtime.h>

#define HID   512
#define BATCH 256
#define SEQ   512
#define NBLK  192
#define NTHR  512
#define HARR  262144   // halves per (layer,parity): hi[16ks][16rtg][4ko][16r][8] + lo
#define HLO   131072   // lo-part offset (halves)

typedef __attribute__((ext_vector_type(8))) _Float16 half8;
typedef __attribute__((ext_vector_type(4))) float f32x4;

typedef __attribute__((address_space(1))) const unsigned int kGlobU32;
typedef __attribute__((address_space(3))) unsigned int kLdsU32;

__device__ __forceinline__ float sigf(float x) {
  return __builtin_amdgcn_rcpf(1.0f + __expf(-x));
}
__device__ __forceinline__ float tanhf_(float x) {
  return 1.0f - 2.0f * __builtin_amdgcn_rcpf(__expf(2.0f * x) + 1.0f);
}

__device__ __forceinline__ half8 cvt8(const float* p) {
  const float4 a = ((const float4*)p)[0];
  const float4 b = ((const float4*)p)[1];
  half8 r;
  r[0] = (_Float16)a.x; r[1] = (_Float16)a.y; r[2] = (_Float16)a.z; r[3] = (_Float16)a.w;
  r[4] = (_Float16)b.x; r[5] = (_Float16)b.y; r[6] = (_Float16)b.z; r[7] = (_Float16)b.w;
  return r;
}

// system-scope (LLC write-through) 2-byte store: no wbL2 fence needed afterwards
__device__ __forceinline__ void store_h_sys(_Float16* p, float v) {
  const _Float16 hv = (_Float16)v;
  const unsigned int u = (unsigned int)__builtin_bit_cast(unsigned short, hv);
  asm volatile("global_store_short %0, %1, off sc0 sc1" :: "v"(p), "v"(u) : "memory");
}

// stage a 64 KiB A-half into LDS buffer BUFB; aux=17 (sc0|sc1): read at LLC, bypass stale L2
#define STAGE(SRC, BUFB) do { \
  _Pragma("unroll") \
  for (int q = 0; q < 8; ++q) { \
    const int s = wave * 8 + q; \
    const _Float16* gsrc = (SRC) + ((s >> 2) * 16 + bt * 4 + (s & 3)) * 512 + lane * 8; \
    __builtin_amdgcn_global_load_lds((kGlobU32*)gsrc, \
        (kLdsU32*)(sA + (BUFB) * 32768 + s * 512), 16, 0, 17); \
  } } while (0)

// one GEMM pass over a staged A-half: 16 k-steps x 4 row-tiles, B from registers
#define MFMA_PASS(WARR, BUFB) do { \
  _Pragma("unroll") \
  for (int ks = 0; ks < 16; ++ks) { \
    _Pragma("unroll") \
    for (int rt = 0; rt < 4; ++rt) { \
      const half8 av = *(const half8*)(sA + (BUFB) * 32768 + (ks * 4 + rt) * 512 + lane * 8); \
      acc[rt] = __builtin_amdgcn_mfma_f32_16x16x32_f16(av, WARR[ks], acc[rt], 0, 0, 0); \
    } } } while (0)

#define VMCNT8 asm volatile("s_waitcnt vmcnt(8)" ::: "memory")
#define VMCNT0 asm volatile("s_waitcnt vmcnt(0)" ::: "memory")
#define SBAR() __builtin_amdgcn_s_barrier()

__device__ __forceinline__ void poll_ge(int* p, int v) {
  while (__hip_atomic_load(p, __ATOMIC_RELAXED, __HIP_MEMORY_SCOPE_AGENT) < v)
    __builtin_amdgcn_s_sleep(1);
}

__global__ __launch_bounds__(NTHR, 2)   // 8 waves = 2/SIMD -> 256-VGPR cap
void lstm3_persistent(const float* __restrict__ tracks,
                      const float* __restrict__ Wih0, const float* __restrict__ bih0,
                      const float* __restrict__ Whh0, const float* __restrict__ bhh0,
                      const float* __restrict__ Wih1, const float* __restrict__ bih1,
                      const float* __restrict__ Whh1, const float* __restrict__ bhh1,
                      const float* __restrict__ Wih2, const float* __restrict__ bih2,
                      const float* __restrict__ Whh2, const float* __restrict__ bhh2,
                      const float* __restrict__ Wpred, const float* __restrict__ bpred,
                      float* __restrict__ out, unsigned short* __restrict__ ws,
                      int* __restrict__ prog)
{
  extern __shared__ _Float16 sA[];   // 2 x 64 KiB A-staging buffers

  const int blk  = blockIdx.x;
  const int bt   = (blk >> 1) & 3;            // batch tile (64 rows); XCD-pair local
  const int rr   = (blk & 1) * 24 + (blk >> 3);  // 0..47
  const int layer = rr >> 4;                  // 0,1,2
  const int ug    = rr & 15;                  // unit group (32 units)
  const int u0    = ug * 32;
  const int tid  = threadIdx.x;
  const int lane = tid & 63;
  const int wave = tid >> 6;
  const int c    = lane & 15;                 // gate col within wave
  const int kod  = lane >> 4;                 // k-octet / D-row group
  const int tg   = c & 3;                     // gate type i,f,g,o
  const int usub = c >> 2;
  const int unit = u0 + wave * 4 + usub;      // this lane's hidden unit
  const int grow = tg * HID + unit;           // global gate row

  const float* Wih = (layer == 0) ? Wih0 : (layer == 1 ? Wih1 : Wih2);
  const float* Whh = (layer == 0) ? Whh0 : (layer == 1 ? Whh1 : Whh2);
  const float* bih = (layer == 0) ? bih0 : (layer == 1 ? bih1 : bih2);
  const float* bhh = (layer == 0) ? bhh0 : (layer == 1 ? bhh1 : bhh2);

  // ---- weights into registers: 16 cols/wave -> 64 VGPR per matrix ----
  half8 whh_r[16], wih_r[16];
  #pragma unroll
  for (int ks = 0; ks < 16; ++ks) {
    const int col = ks * 32 + kod * 8;
    whh_r[ks] = cvt8(Whh + (size_t)grow * 512 + col);
    if (layer > 0) wih_r[ks] = cvt8(Wih + (size_t)grow * 512 + col);
    else { half8 z = {}; wih_r[ks] = z; }
  }

  const float bias_c = bih[grow] + bhh[grow];
  float w0_c = 0.f, w1_c = 0.f;
  if (layer == 0) { w0_c = Wih0[grow * 2]; w1_c = Wih0[grow * 2 + 1]; }

  float cst[16];
  #pragma unroll
  for (int r = 0; r < 16; ++r) cst[r] = 0.f;

  _Float16* hws = (_Float16*)ws;
  const int sb = (lane & 48) | (c & 12);      // shuffle base: 4 gates of my unit-slot
  const int myflag   = (layer * 4 + bt) * 32;
  const int prodflag = ((layer - 1) * 4 + bt) * 32;
  const int consflag = ((layer + 1) * 4 + bt) * 32;

  for (int t = 0; t < SEQ; ++t) {
    const int pr = (t + 1) & 1;
    const int pw = t & 1;

    // ---- distributed sync: 3 conditions polled by 3 waves in parallel; no fences ----
    if (tid == 0) {
      if (layer > 0) poll_ge(&prog[prodflag], 16 * (t + 1));
    } else if (tid == 64) {
      if (t > 0) poll_ge(&prog[myflag], 16 * t);
    } else if (tid == 128) {
      if (layer < 2 && t >= 2) poll_ge(&prog[consflag], 16 * (t - 1));
    }
    __syncthreads();

    const _Float16* Hs = hws + (size_t)(layer * 2 + pr) * HARR;
    const _Float16* Xs = (layer > 0) ? hws + (size_t)((layer - 1) * 2 + pw) * HARR : (const _Float16*)0;
    const bool doH = (t > 0);
    const bool doX = (layer > 0);

    f32x4 acc[4];
    #pragma unroll
    for (int rt = 0; rt < 4; ++rt) { acc[rt][0]=0.f; acc[rt][1]=0.f; acc[rt][2]=0.f; acc[rt][3]=0.f; }

    // ---- pipelined passes: stage(i+2) overlaps mfma(i); vmcnt counted, never 0 mid-loop ----
    if (doH && doX) {
      STAGE(Hs, 0); STAGE(Hs + HLO, 1); VMCNT8; SBAR();
      MFMA_PASS(whh_r, 0); SBAR(); STAGE(Xs, 0);       VMCNT8; SBAR();
      MFMA_PASS(whh_r, 1); SBAR(); STAGE(Xs + HLO, 1); VMCNT8; SBAR();
      MFMA_PASS(wih_r, 0); SBAR();                     VMCNT0; SBAR();
      MFMA_PASS(wih_r, 1);
    } else if (doH) {
      STAGE(Hs, 0); STAGE(Hs + HLO, 1); VMCNT8; SBAR();
      MFMA_PASS(whh_r, 0); SBAR();                     VMCNT0; SBAR();
      MFMA_PASS(whh_r, 1);
    } else if (doX) {
      STAGE(Xs, 0); STAGE(Xs + HLO, 1); VMCNT8; SBAR();
      MFMA_PASS(wih_r, 0); SBAR();                     VMCNT0; SBAR();
      MFMA_PASS(wih_r, 1);
    }

    // ---- elementwise ----
    _Float16* wr = hws + (size_t)(layer * 2 + pw) * HARR;
    #pragma unroll
    for (int rt = 0; rt < 4; ++rt) {
      float2 xv[4];
      if (layer == 0) {
        #pragma unroll
        for (int rg = 0; rg < 4; ++rg) {
          const int m = bt * 64 + rt * 16 + kod * 4 + rg;
          xv[rg] = ((const float2*)tracks)[(size_t)m * SEQ + t];
        }
      }
      #pragma unroll
      for (int rg = 0; rg < 4; ++rg) {
        float g = acc[rt][rg] + bias_c;
        if (layer == 0) g += w0_c * xv[rg].x + w1_c * xv[rg].y;
        const float gi_ = __shfl(g, sb | 0, 64);
        const float gf_ = __shfl(g, sb | 1, 64);
        const float gg_ = __shfl(g, sb | 2, 64);
        const float go_ = __shfl(g, sb | 3, 64);
        const float iv = sigf(gi_);
        const float fv = sigf(gf_);
        const float gn = tanhf_(gg_);
        const float ov = sigf(go_);
        const float cn = fv * cst[rt * 4 + rg] + iv * gn;
        cst[rt * 4 + rg] = cn;
        const float hn = ov * tanhf_(cn);
        if (tg == 0) {   // one gate-group writes h for its unit (system-scope, LLC)
          const int r16 = kod * 4 + rg;
          const size_t off = ((size_t)((unit >> 5) * 16 + bt * 4 + rt) * 4
                              + ((unit >> 3) & 3)) * 128 + r16 * 8 + (unit & 7);
          store_h_sys(wr + off, hn);
          store_h_sys(wr + off + HLO, hn - (float)((_Float16)hn));
        }
      }
    }

    // ---- publish: syncthreads drains vmcnt (stores at LLC) -> relaxed RMW, no fence ----
    __syncthreads();
    if (tid == 0)
      __hip_atomic_fetch_add(&prog[myflag], 1, __ATOMIC_RELAXED,
                             __HIP_MEMORY_SCOPE_AGENT);
  }

  // ---- final sync: all layer-2 tiles done; one acquire fence for normal-load epilogue ----
  if (tid == 0) {
    #pragma unroll
    for (int b = 0; b < 4; ++b) poll_ge(&prog[(8 + b) * 32], 16 * SEQ);
    __builtin_amdgcn_fence(__ATOMIC_ACQUIRE, "agent");
  }
  __syncthreads();

  // ---- output head: out[b][p] = elu(h2_final[b]) . Wpred[p] + bpred[p] ----
  const int gw = blk * 8 + wave;
  if (gw < BATCH * 4) {
    const int b = gw >> 2;
    const int p = gw & 3;
    const _Float16* Hf = hws + (size_t)5 * HARR;   // layer 2, parity 1 (t=511)
    const size_t base = ((size_t)((lane >> 2) * 16 + (b >> 4)) * 4 + (lane & 3)) * 128
                        + (size_t)(b & 15) * 8;
    const half8 hh = *(const half8*)(Hf + base);
    const half8 hl = *(const half8*)(Hf + HLO + base);
    float a = 0.f;
    #pragma unroll
    for (int j = 0; j < 8; ++j) {
      const float hv = (float)hh[j] + (float)hl[j];
      const float e = hv > 0.f ? hv : expm1f(hv);
      a += e * Wpred[p * HID + lane * 8 + j];
    }
    #pragma unroll
    for (int off = 32; off > 0; off >>= 1) a += __shfl_down(a, off, 64);
    if (lane == 0) out[b * 4 + p] = a + bpred[p];
  }
}

extern "C" void kernel_launch(void* const* d_in, const int* in_sizes, int n_in,
                              void* d_out, int out_size, void* d_ws, size_t ws_size,
                              hipStream_t stream) {
  const float* tracks = (const float*)d_in[0];
  const float* Wih0  = (const float*)d_in[1];
  const float* bih0  = (const float*)d_in[2];
  const float* Whh0  = (const float*)d_in[3];
  const float* bhh0  = (const float*)d_in[4];
  const float* Wih1  = (const float*)d_in[5];
  const float* bih1  = (const float*)d_in[6];
  const float* Whh1  = (const float*)d_in[7];
  const float* bhh1  = (const float*)d_in[8];
  const float* Wih2  = (const float*)d_in[9];
  const float* bih2  = (const float*)d_in[10];
  const float* Whh2  = (const float*)d_in[11];
  const float* bhh2  = (const float*)d_in[12];
  const float* Wpred = (const float*)d_in[13];
  const float* bpred = (const float*)d_in[14];
  float* out = (float*)d_out;
  unsigned short* ws = (unsigned short*)d_ws;
  int* prog = (int*)((char*)d_ws + (size_t)6 * HARR * 2);   // 12 padded counters

  hipFuncSetAttribute(reinterpret_cast<const void*>(lstm3_persistent),
                      hipFuncAttributeMaxDynamicSharedMemorySize, 131072);

  // zero only the progress counters (h needs no init: t=0 skips the hidden pass)
  hipMemsetAsync(prog, 0, 12 * 32 * sizeof(int), stream);

  void* args[] = { &tracks, &Wih0, &bih0, &Whh0, &bhh0,
                   &Wih1, &bih1, &Whh1, &bhh1,
                   &Wih2, &bih2, &Whh2, &bhh2,
                   &Wpred, &bpred, &out, &ws, &prog };
  hipLaunchCooperativeKernel(reinterpret_cast<void*>(lstm3_persistent),
                             dim3(NBLK), dim3(NTHR), args, 131072, stream);
}

// Round 7
// 4182.489 us; speedup vs baseline: 5.5916x; 1.9791x over previous
//
#include <hip/hip_runtime.h>

#define HID   512
#define BATCH 256
#define SEQ   512
#define NBLK  192
#define NTHR  512
#define HARR2 131072   // halves per (layer,parity): [16ks][16 bt*4+rt][4ko][16row][8j]

typedef __attribute__((ext_vector_type(8))) _Float16 half8;
typedef __attribute__((ext_vector_type(4))) float f32x4;

typedef __attribute__((address_space(1))) const unsigned int kGlobU32;
typedef __attribute__((address_space(3))) unsigned int kLdsU32;

__device__ __forceinline__ float sigf(float x) {
  return __builtin_amdgcn_rcpf(1.0f + __expf(-x));
}
__device__ __forceinline__ float tanhf_(float x) {
  return 1.0f - 2.0f * __builtin_amdgcn_rcpf(__expf(2.0f * x) + 1.0f);
}

__device__ __forceinline__ half8 cvt8(const float* p) {
  const float4 a = ((const float4*)p)[0];
  const float4 b = ((const float4*)p)[1];
  half8 r;
  r[0] = (_Float16)a.x; r[1] = (_Float16)a.y; r[2] = (_Float16)a.z; r[3] = (_Float16)a.w;
  r[4] = (_Float16)b.x; r[5] = (_Float16)b.y; r[6] = (_Float16)b.z; r[7] = (_Float16)b.w;
  return r;
}

// system-scope coalesced 8B store (write-through LLC, no wbL2 fence needed)
__device__ __forceinline__ void store_sys8(_Float16* p, unsigned long long v) {
  asm volatile("global_store_dwordx2 %0, %1, off sc0 sc1" :: "v"(p), "v"(v) : "memory");
}

// stage a 64 KiB A-tile into LDS buffer BUFB; aux=17 (sc0|sc1): read at LLC, bypass stale L2
#define STAGE(SRC, BUFB) do { \
  _Pragma("unroll") \
  for (int q = 0; q < 8; ++q) { \
    const int s = wave * 8 + q; \
    const _Float16* gsrc = (SRC) + ((s >> 2) * 16 + bt * 4 + (s & 3)) * 512 + lane * 8; \
    __builtin_amdgcn_global_load_lds((kGlobU32*)gsrc, \
        (kLdsU32*)(sA + (BUFB) * 32768 + s * 512), 16, 0, 17); \
  } } while (0)

// one GEMM pass over a staged A-tile: 16 k-steps x 4 row-tiles, B from registers
#define MFMA_PASS(WARR, BUFB) do { \
  _Pragma("unroll") \
  for (int ks = 0; ks < 16; ++ks) { \
    _Pragma("unroll") \
    for (int rt = 0; rt < 4; ++rt) { \
      const half8 av = *(const half8*)(sA + (BUFB) * 32768 + (ks * 4 + rt) * 512 + lane * 8); \
      acc[rt] = __builtin_amdgcn_mfma_f32_16x16x32_f16(av, WARR[ks], acc[rt], 0, 0, 0); \
    } } } while (0)

#define VMCNT8 asm volatile("s_waitcnt vmcnt(8)" ::: "memory")
#define VMCNT0 asm volatile("s_waitcnt vmcnt(0)" ::: "memory")
#define SBAR() __builtin_amdgcn_s_barrier()

__device__ __forceinline__ void poll_ge(int* p, int v) {
  while (__hip_atomic_load(p, __ATOMIC_RELAXED, __HIP_MEMORY_SCOPE_AGENT) < v)
    __builtin_amdgcn_s_sleep(1);
}

__global__ __launch_bounds__(NTHR, 2)   // 8 waves = 2/SIMD -> 256-VGPR cap
void lstm3_persistent(const float* __restrict__ tracks,
                      const float* __restrict__ Wih0, const float* __restrict__ bih0,
                      const float* __restrict__ Whh0, const float* __restrict__ bhh0,
                      const float* __restrict__ Wih1, const float* __restrict__ bih1,
                      const float* __restrict__ Whh1, const float* __restrict__ bhh1,
                      const float* __restrict__ Wih2, const float* __restrict__ bih2,
                      const float* __restrict__ Whh2, const float* __restrict__ bhh2,
                      const float* __restrict__ Wpred, const float* __restrict__ bpred,
                      float* __restrict__ out, unsigned short* __restrict__ ws,
                      int* __restrict__ prog)
{
  extern __shared__ _Float16 sA[];      // 2 x 64 KiB A-staging buffers (dynamic)
  __shared__ _Float16 sB[2048];         // 4 KiB h-store bounce (static)

  const int blk  = blockIdx.x;
  const int bt   = (blk >> 1) & 3;            // batch tile (64 rows); XCD-pair local
  const int rr   = (blk & 1) * 24 + (blk >> 3);  // 0..47
  const int layer = rr >> 4;                  // 0,1,2
  const int ug    = rr & 15;                  // unit group (32 units)
  const int u0    = ug * 32;
  const int tid  = threadIdx.x;
  const int lane = tid & 63;
  const int wave = tid >> 6;
  const int c    = lane & 15;                 // gate col within wave
  const int kod  = lane >> 4;                 // k-octet / D-row group
  const int tg   = c & 3;                     // gate type i,f,g,o
  const int usub = c >> 2;
  const int unit = u0 + wave * 4 + usub;      // this lane's hidden unit
  const int grow = tg * HID + unit;           // global gate row

  const float* Wih = (layer == 0) ? Wih0 : (layer == 1 ? Wih1 : Wih2);
  const float* Whh = (layer == 0) ? Whh0 : (layer == 1 ? Whh1 : Whh2);
  const float* bih = (layer == 0) ? bih0 : (layer == 1 ? bih1 : bih2);
  const float* bhh = (layer == 0) ? bhh0 : (layer == 1 ? bhh1 : bhh2);

  // ---- weights into registers/AGPRs: 16 cols/wave -> 64 regs per matrix ----
  half8 whh_r[16], wih_r[16];
  #pragma unroll
  for (int ks = 0; ks < 16; ++ks) {
    const int col = ks * 32 + kod * 8;
    whh_r[ks] = cvt8(Whh + (size_t)grow * 512 + col);
    if (layer > 0) wih_r[ks] = cvt8(Wih + (size_t)grow * 512 + col);
    else { half8 z = {}; wih_r[ks] = z; }
  }

  const float bias_c = bih[grow] + bhh[grow];
  float w0_c = 0.f, w1_c = 0.f;
  if (layer == 0) { w0_c = Wih0[grow * 2]; w1_c = Wih0[grow * 2 + 1]; }

  float cst[16];
  #pragma unroll
  for (int r = 0; r < 16; ++r) cst[r] = 0.f;

  _Float16* hws = (_Float16*)ws;              // 6 arrays of HARR2 halves
  const int sb = (lane & 48) | (c & 12);      // shuffle base: 4 gates of my unit-slot
  const int myflag   = (layer * 4 + bt) * 32;
  const int prodflag = ((layer - 1) * 4 + bt) * 32;
  const int consflag = ((layer + 1) * 4 + bt) * 32;
  // bounce->global store coords (uniform per thread)
  const int st_rt = tid >> 7;
  const int st_wi = (tid * 4) & 511;

  for (int t = 0; t < SEQ; ++t) {
    const int pr = (t + 1) & 1;
    const int pw = t & 1;

    // ---- distributed sync: 3 conditions polled by 3 waves in parallel; no fences ----
    if (tid == 0) {
      if (layer > 0) poll_ge(&prog[prodflag], 16 * (t + 1));
    } else if (tid == 64) {
      if (t > 0) poll_ge(&prog[myflag], 16 * t);
    } else if (tid == 128) {
      if (layer < 2 && t >= 2) poll_ge(&prog[consflag], 16 * (t - 1));
    }
    __syncthreads();

    const _Float16* Hs = hws + (size_t)(layer * 2 + pr) * HARR2;
    const _Float16* Xs = (layer > 0) ? hws + (size_t)((layer - 1) * 2 + pw) * HARR2 : (const _Float16*)0;
    const bool doH = (t > 0);
    const bool doX = (layer > 0);

    f32x4 acc[4];
    #pragma unroll
    for (int rt = 0; rt < 4; ++rt) { acc[rt][0]=0.f; acc[rt][1]=0.f; acc[rt][2]=0.f; acc[rt][3]=0.f; }

    // ---- single stage phase: both tiles resident; X-loads overlap H-GEMM ----
    if (doH) STAGE(Hs, 0);
    if (doX) STAGE(Xs, 1);
    if (doH && doX) {
      VMCNT8; SBAR();             // all waves' H-tile complete
      MFMA_PASS(whh_r, 0);
      VMCNT0; SBAR();             // all waves' X-tile complete
      MFMA_PASS(wih_r, 1);
    } else if (doH) {
      VMCNT0; SBAR();
      MFMA_PASS(whh_r, 0);
    } else if (doX) {
      VMCNT0; SBAR();
      MFMA_PASS(wih_r, 1);
    }

    // ---- elementwise; h written to LDS bounce ----
    #pragma unroll
    for (int rt = 0; rt < 4; ++rt) {
      float2 xv[4];
      if (layer == 0) {
        #pragma unroll
        for (int rg = 0; rg < 4; ++rg) {
          const int m = bt * 64 + rt * 16 + kod * 4 + rg;
          xv[rg] = ((const float2*)tracks)[(size_t)m * SEQ + t];
        }
      }
      #pragma unroll
      for (int rg = 0; rg < 4; ++rg) {
        float g = acc[rt][rg] + bias_c;
        if (layer == 0) g += w0_c * xv[rg].x + w1_c * xv[rg].y;
        const float gi_ = __shfl(g, sb | 0, 64);
        const float gf_ = __shfl(g, sb | 1, 64);
        const float gg_ = __shfl(g, sb | 2, 64);
        const float go_ = __shfl(g, sb | 3, 64);
        const float iv = sigf(gi_);
        const float fv = sigf(gf_);
        const float gn = tanhf_(gg_);
        const float ov = sigf(go_);
        const float cn = fv * cst[rt * 4 + rg] + iv * gn;
        cst[rt * 4 + rg] = cn;
        const float hn = ov * tanhf_(cn);
        if (tg == 0) {   // one gate-group writes h for its unit -> LDS bounce
          const int r16 = kod * 4 + rg;   // row within 16-row tile
          sB[rt * 512 + ((unit >> 3) & 3) * 128 + r16 * 8 + (unit & 7)] = (_Float16)hn;
        }
      }
    }

    // ---- coalesced system-scope store of the 4 KiB h-tile ----
    __syncthreads();   // bounce visible
    {
      _Float16* wr = hws + (size_t)(layer * 2 + pw) * HARR2;
      const unsigned long long v = *(const unsigned long long*)(sB + tid * 4);
      store_sys8(wr + ((size_t)(ug * 16 + bt * 4 + st_rt) << 9) + st_wi, v);
    }
    VMCNT0;            // own stores at LLC
    __syncthreads();   // all waves' stores at LLC
    if (tid == 0)
      __hip_atomic_fetch_add(&prog[myflag], 1, __ATOMIC_RELAXED,
                             __HIP_MEMORY_SCOPE_AGENT);
  }

  // ---- final sync: all layer-2 tiles done; one acquire fence for normal-load epilogue ----
  if (tid == 0) {
    #pragma unroll
    for (int b = 0; b < 4; ++b) poll_ge(&prog[(8 + b) * 32], 16 * SEQ);
    __builtin_amdgcn_fence(__ATOMIC_ACQUIRE, "agent");
  }
  __syncthreads();

  // ---- output head: out[b][p] = elu(h2_final[b]) . Wpred[p] + bpred[p] ----
  const int gw = blk * 8 + wave;
  if (gw < BATCH * 4) {
    const int b = gw >> 2;
    const int p = gw & 3;
    const _Float16* Hf = hws + (size_t)5 * HARR2;   // layer 2, parity 1 (t=511)
    const size_t base = ((size_t)((lane >> 2) * 16 + (b >> 4)) * 4 + (lane & 3)) * 128
                        + (size_t)(b & 15) * 8;
    const half8 hh = *(const half8*)(Hf + base);
    float a = 0.f;
    #pragma unroll
    for (int j = 0; j < 8; ++j) {
      const float hv = (float)hh[j];
      const float e = hv > 0.f ? hv : expm1f(hv);
      a += e * Wpred[p * HID + lane * 8 + j];
    }
    #pragma unroll
    for (int off = 32; off > 0; off >>= 1) a += __shfl_down(a, off, 64);
    if (lane == 0) out[b * 4 + p] = a + bpred[p];
  }
}

extern "C" void kernel_launch(void* const* d_in, const int* in_sizes, int n_in,
                              void* d_out, int out_size, void* d_ws, size_t ws_size,
                              hipStream_t stream) {
  const float* tracks = (const float*)d_in[0];
  const float* Wih0  = (const float*)d_in[1];
  const float* bih0  = (const float*)d_in[2];
  const float* Whh0  = (const float*)d_in[3];
  const float* bhh0  = (const float*)d_in[4];
  const float* Wih1  = (const float*)d_in[5];
  const float* bih1  = (const float*)d_in[6];
  const float* Whh1  = (const float*)d_in[7];
  const float* bhh1  = (const float*)d_in[8];
  const float* Wih2  = (const float*)d_in[9];
  const float* bih2  = (const float*)d_in[10];
  const float* Whh2  = (const float*)d_in[11];
  const float* bhh2  = (const float*)d_in[12];
  const float* Wpred = (const float*)d_in[13];
  const float* bpred = (const float*)d_in[14];
  float* out = (float*)d_out;
  unsigned short* ws = (unsigned short*)d_ws;
  int* prog = (int*)((char*)d_ws + (size_t)6 * HARR2 * 2);   // 12 padded counters

  hipFuncSetAttribute(reinterpret_cast<const void*>(lstm3_persistent),
                      hipFuncAttributeMaxDynamicSharedMemorySize, 131072);

  // zero only the progress counters (h needs no init: t=0 skips the hidden pass)
  hipMemsetAsync(prog, 0, 12 * 32 * sizeof(int), stream);

  void* args[] = { &tracks, &Wih0, &bih0, &Whh0, &bhh0,
                   &Wih1, &bih1, &Whh1, &bhh1,
                   &Wih2, &bih2, &Whh2, &bhh2,
                   &Wpred, &bpred, &out, &ws, &prog };
  hipLaunchCooperativeKernel(reinterpret_cast<void*>(lstm3_persistent),
                             dim3(NBLK), dim3(NTHR), args, 131072, stream);
}